// Round 15
// baseline (1004.483 us; speedup 1.0000x reference)
//
#include <hip/hip_runtime.h>

typedef _Float16 f16;
typedef _Float16 f16x4 __attribute__((ext_vector_type(4)));
typedef _Float16 f16x8 __attribute__((ext_vector_type(8)));
typedef float f32x4 __attribute__((ext_vector_type(4)));
typedef int i32x4 __attribute__((ext_vector_type(4)));

#define TLEN 2048
#define TPAD 2050           // gates3 time extent (2 pad steps for prefetch)
#define NCOL 640            // 160 units x 4 gates, col = u*4 + G
#define GSTEP (16 * NCOL)   // f16 elements per timestep in gates3 [t][b][col]
#define SPITCH 1100         // LDS image pitch: 16B-aligned, <=2-way bank alias
#define K1 1.4426950408889634f
#define K2 2.8853900817779268f

// ---------------------------------------------------------------------------
// Fused conv + gates GEMM, SELF-INITIALIZING (no prep kernels).
// 256 blocks x 512 threads, one block per 8-timestep chunk.
// Init: each wave builds its 5x5 w_ih f16 fragments (pre-scaled per gate:
// i,f,o -K1; g +K2) and bias directly from raw w_ih/b_ih/b_hh.
// Per timestep: stage 16 images (float4), conv 17->4 + ReLU into s_y
// (float4 LDS reads), then 8 timesteps of gates GEMM (A from LDS s_y).
// Output gates3 [t][b(16)][col(640)] f16, col = unit*4 + gate.
// ---------------------------------------------------------------------------
__global__ __launch_bounds__(512, 1) void conv_gemm(
    const float* __restrict__ inp, const float* __restrict__ cw,
    const float* __restrict__ cb,
    const float* __restrict__ w_ih, const float* __restrict__ b_ih,
    const float* __restrict__ b_hh,
    f16* __restrict__ gates3)
{
    __shared__ __align__(16) float s_in[16][SPITCH];
    __shared__ __align__(16) f16 s_y[8][16][168];
    __shared__ float s_w[612];
    const int tid = threadIdx.x, w = tid >> 6, lane = tid & 63;
    const int col = lane & 15, grp = lane >> 4;
    for (int i = tid; i < 612; i += 512) s_w[i] = cw[i];

    // --- self-init: w_ih fragments + bias (frag layout proven r5-r14) ---
    f16x8 bfr[5][5];
    float bb[5];
    #pragma unroll
    for (int i = 0; i < 5; ++i) {
        const int colg = (w * 5 + i) * 16 + col;
        const int u = colg >> 2, G = colg & 3;
        const float sc = (G == 2) ? K2 : -K1;
        const bool valid = (u < 150);
        const int row = valid ? G * 150 + u : 0;
        #pragma unroll
        for (int kt = 0; kt < 5; ++kt) {
            const int k0 = kt * 32 + grp * 8;        // k0..k0+7
            f16x8 v;
            #pragma unroll
            for (int e = 0; e < 8; ++e) v[e] = (f16)0.f;
            if (valid && k0 < 144) {                 // kt=4,grp>=2 -> pad zeros
                const float* p = w_ih + (size_t)row * 144 + k0;
                #pragma unroll
                for (int e = 0; e < 8; ++e) v[e] = (f16)(p[e] * sc);
            }
            bfr[i][kt] = v;
        }
        bb[i] = valid ? (b_ih[row] + b_hh[row]) * sc : 0.f;
    }

    // conv role: cb_b = batch, unit -> (oc, oy)
    const int cb_b = tid & 15, unit = tid >> 4;      // unit 0..31
    const int oc = unit / 6, oy = unit % 6;          // valid if unit < 24
    const float cbias = (unit < 24) ? cb[oc] : 0.f;
    __syncthreads();

    const int t0 = blockIdx.x * 8;
    for (int tl = 0; tl < 8; ++tl) {
        const int t = t0 + tl;
        __syncthreads();   // previous tl's conv reads done before restaging
        {   // stage 16 images, float4 (32 threads per image, coalesced)
            const int si = tid >> 5, l2 = tid & 31;
            const float4* ip =
                (const float4*)(inp + ((size_t)si * TLEN + t) * 1088);
            for (int k = l2; k < 272; k += 32)
                *(float4*)(&s_in[si][k * 4]) = ip[k];
        }
        __syncthreads();
        if (unit < 24) {
            const float* wp = s_w + oc * 153;
            float acc[6] = {cbias, cbias, cbias, cbias, cbias, cbias};
            #pragma unroll 1
            for (int ic = 0; ic < 17; ++ic) {
                #pragma unroll
                for (int ky = 0; ky < 3; ++ky) {
                    const float* r = &s_in[cb_b][ic * 64 + (oy + ky) * 8];
                    const float4 f0 = *(const float4*)r;
                    const float4 f1 = *(const float4*)(r + 4);
                    const float w0 = wp[ic * 9 + ky * 3 + 0];
                    const float w1 = wp[ic * 9 + ky * 3 + 1];
                    const float w2 = wp[ic * 9 + ky * 3 + 2];
                    acc[0] += f0.x * w0 + f0.y * w1 + f0.z * w2;
                    acc[1] += f0.y * w0 + f0.z * w1 + f0.w * w2;
                    acc[2] += f0.z * w0 + f0.w * w1 + f1.x * w2;
                    acc[3] += f0.w * w0 + f1.x * w1 + f1.y * w2;
                    acc[4] += f1.x * w0 + f1.y * w1 + f1.z * w2;
                    acc[5] += f1.y * w0 + f1.z * w1 + f1.w * w2;
                }
            }
            #pragma unroll
            for (int ox = 0; ox < 6; ++ox)
                s_y[tl][cb_b][oc * 36 + oy * 6 + ox] = (f16)fmaxf(acc[ox], 0.f);
        } else if (unit == 24) {
            #pragma unroll
            for (int k = 0; k < 16; ++k) s_y[tl][cb_b][144 + k] = (f16)0.f;
        }
    }
    __syncthreads();
    // gates GEMM for the 8 timesteps (A from LDS s_y, B-fragments resident)
    for (int tl = 0; tl < 8; ++tl) {
        const int t = t0 + tl;
        f16x8 a[5];
        #pragma unroll
        for (int kt = 0; kt < 5; ++kt)
            a[kt] = *(const f16x8*)(&s_y[tl][col][kt * 32 + grp * 8]);
        #pragma unroll
        for (int i = 0; i < 5; ++i) {
            f32x4 acc = {0.f, 0.f, 0.f, 0.f};
            #pragma unroll
            for (int kt = 0; kt < 5; ++kt)
                acc = __builtin_amdgcn_mfma_f32_16x16x32_f16(a[kt], bfr[i][kt], acc, 0, 0, 0);
            const int colg = (w * 5 + i) * 16 + col;
            #pragma unroll
            for (int r = 0; r < 4; ++r)
                gates3[((size_t)(t * 16 + grp * 4 + r)) * NCOL + colg] =
                    (f16)(acc[r] + bb[i]);
        }
    }
}

// ---------------------------------------------------------------------------
// Scan step (i8 MFMA; hot loop bit-identical to r14's proven version).
// ---------------------------------------------------------------------------
__device__ __forceinline__ void lstm_stepQ(
    int t, int cur, f16x4& pfu, f16x4& pfc, const f16*& pLoad,
    const i32x4 (&afrag)[5][3], const f32x4& scv,
    signed char* hqs, f16* hfs, float& cst,
    int grp, int sel, bool wr, int u)
{
    // 1) Issue next-next-step gates load first (longest latency).
    const f16x4 pnew = *(const f16x4*)pLoad;
    pLoad += GSTEP;

    // 2) B-fragment reads: 3 x b128 of quantized h (broadcast, conflict-free).
    const signed char* hr = hqs + cur * 192 + grp * 16;
    i32x4 bf[3];
    #pragma unroll
    for (int kt = 0; kt < 3; ++kt)
        bf[kt] = *(const i32x4*)(hr + kt * 64);

    // 3) In the read shadow: convert this step's unit-gates (f16->f32).
    float gx0 = (float)pfu[0], gx1 = (float)pfu[1];
    float gx2 = (float)pfu[2], gx3 = (float)pfu[3];
    pfc = pnew;

    // 4) i8 MFMA: 5 tiles x 3 kt, integer C-init 0.
    const i32x4 zc = {0, 0, 0, 0};
    i32x4 acc[5];
    #pragma unroll
    for (int i = 0; i < 5; ++i)
        acc[i] = __builtin_amdgcn_mfma_i32_16x16x64_i8(afrag[i][0], bf[0], zc, 0, 0, 0);
    #pragma unroll
    for (int kt = 1; kt < 3; ++kt)
        #pragma unroll
        for (int i = 0; i < 5; ++i)
            acc[i] = __builtin_amdgcn_mfma_i32_16x16x64_i8(afrag[i][kt], bf[kt], acc[i], 0, 0, 0);

    // 5) Select this lane's tile.
    int s0 = acc[0][0], s1 = acc[0][1], s2 = acc[0][2], s3 = acc[0][3];
    #pragma unroll
    for (int i = 1; i < 5; ++i) {
        const bool p = (sel == i);
        s0 = p ? acc[i][0] : s0;
        s1 = p ? acc[i][1] : s1;
        s2 = p ? acc[i][2] : s2;
        s3 = p ? acc[i][3] : s3;
    }

    // 6) Dequant + add gates_x (dsc carries gate prescale/sign).
    const float g0 = fmaf((float)s0, scv[0], gx0);
    const float g1 = fmaf((float)s1, scv[1], gx1);
    const float g2 = fmaf((float)s2, scv[2], gx2);
    const float g3 = fmaf((float)s3, scv[3], gx3);

    // 7) Shared-denominator activation: 5 exp2 + 3 rcp; all paths finite.
    const float ei = __builtin_amdgcn_exp2f(g0);                // e^{-i}
    const float ef = __builtin_amdgcn_exp2f(g1);                // e^{-f}
    const float eg = __builtin_amdgcn_exp2f(fminf(g2, 38.f));   // e^{2g}
    const float eo = __builtin_amdgcn_exp2f(g3);                // e^{-o}
    const float dig = (1.f + ei) * (eg + 1.f);
    const float c = cst * __builtin_amdgcn_rcpf(1.f + ef)
                  + (eg - 1.f) * __builtin_amdgcn_rcpf(dig);
    cst = c;
    const float ec = __builtin_amdgcn_exp2f(fminf(K2 * c, 80.f));
    const float h = (ec - 1.f) * __builtin_amdgcn_rcpf((1.f + eo) * (ec + 1.f));

    // 8) Quantize + write h (i8); f16 copy only on the last step.
    if (wr) hqs[(cur ^ 1) * 192 + u] = (signed char)(int)rintf(127.f * h);
    if (t == TLEN - 1 && wr) hfs[u] = (f16)h;

    // 9) Drain LDS ops only; ONE raw barrier per step (vmcnt stays hot).
    asm volatile("s_waitcnt lgkmcnt(0)" ::: "memory");
    __builtin_amdgcn_s_barrier();
    __builtin_amdgcn_sched_barrier(0);
}

// ---------------------------------------------------------------------------
// Batch-parallel persistent i8 LSTM scan, SELF-INITIALIZING: cooperative
// per-WG rowmax of w_hh in LDS, then each lane quantizes its own 5x3 i8
// A-fragments and dequant scales (bit-identical math to the old prep
// kernel).  16 WGs (one batch row each), 512 threads = 8 waves = 2/SIMD.
// ---------------------------------------------------------------------------
__global__ __launch_bounds__(512, 1) void lstm_scan(
    const f16* __restrict__ gates3, const float* __restrict__ w_hh,
    const float* __restrict__ last_w, const float* __restrict__ last_b,
    float* __restrict__ out)
{
    __shared__ __align__(16) signed char hq[2 * 192];
    __shared__ __align__(16) f16 hf[160];
    __shared__ float s_rm[600];
    const int b = blockIdx.x;
    const int tid = threadIdx.x, w = tid >> 6, lane = tid & 63;
    const int col = lane & 15, grp = lane >> 4;
    const int sel = (col < 5) ? col : ((col < 10) ? col - 5 : ((col < 15) ? col - 10 : 0));
    const bool wr = (col < 5);
    const int u = 20 * w + 4 * sel + grp;

    for (int i = tid; i < 2 * 192; i += 512) hq[i] = 0;

    // --- cooperative per-row |max| of w_hh (600 rows x 150) ---
    for (int r = tid; r < 600; r += 512) {
        const float* p = w_hh + (size_t)r * 150;
        float m = 0.f;
        for (int k = 0; k < 150; k += 2) {
            m = fmaxf(m, fabsf(p[k]));
            m = fmaxf(m, fabsf(p[k + 1]));
        }
        s_rm[r] = m;
    }
    __syncthreads();

    // --- self-quantized i8 A-fragments (same k-map as r12-r14 prep) ---
    i32x4 afrag[5][3];
    #pragma unroll
    for (int i = 0; i < 5; ++i) {
        const int colg = (5 * w + i) * 16 + col;
        const int uu = colg >> 2, G = colg & 3;
        const bool valid = (uu < 150);
        const int row = valid ? G * 150 + uu : 0;
        const float rm = s_rm[row];
        const float qs = (valid && rm > 0.f) ? 127.f / rm : 0.f;
        const float* p = w_hh + (size_t)row * 150;
        #pragma unroll
        for (int kt = 0; kt < 3; ++kt) {
            int wv[4] = {0, 0, 0, 0};
            #pragma unroll
            for (int byte = 0; byte < 16; ++byte) {
                const int k = kt * 64 + grp * 16 + byte;
                int q = 0;
                if (k < 150) q = (int)rintf(p[k] * qs);
                wv[byte >> 2] |= (q & 255) << ((byte & 3) * 8);
            }
            afrag[i][kt] = (i32x4){wv[0], wv[1], wv[2], wv[3]};
        }
    }
    // --- dequant scales for this lane's unit ---
    f32x4 scv;
    {
        const bool vu = (u < 150);
        #pragma unroll
        for (int G = 0; G < 4; ++G) {
            const float sc = (G == 2) ? K2 : -K1;
            const int idx = vu ? G * 150 + u : 0;
            scv[G] = vu ? sc * s_rm[idx] * (1.f / 16129.f) : 0.f;
        }
    }
    float cst = 0.f;
    __syncthreads();

    const f16* gbu = gates3 + (size_t)b * NCOL + 80 * w + 16 * sel + 4 * grp;
    f16x4 pA = *(const f16x4*)(gbu);
    f16x4 pB = *(const f16x4*)(gbu + (size_t)1 * GSTEP);
    const f16* pLoad = gbu + (size_t)2 * GSTEP;

    #pragma unroll 1
    for (int tb = 0; tb < TLEN; tb += 2) {
        lstm_stepQ(tb,     0, pA, pA, pLoad, afrag, scv, hq, hf, cst, grp, sel, wr, u);
        lstm_stepQ(tb + 1, 1, pB, pB, pLoad, afrag, scv, hq, hf, cst, grp, sel, wr, u);
    }

    if (tid < 2) {
        float s = last_b[tid];
        for (int j = 0; j < 150; ++j)
            s += (float)hf[j] * last_w[tid * 150 + j];
        out[b * 2 + tid] = s;
    }
}

// ---------------------------------------------------------------------------
extern "C" void kernel_launch(void* const* d_in, const int* in_sizes, int n_in,
                              void* d_out, int out_size, void* d_ws, size_t ws_size,
                              hipStream_t stream) {
    const float* inp    = (const float*)d_in[0];
    const float* conv_w = (const float*)d_in[1];
    const float* conv_b = (const float*)d_in[2];
    const float* w_ih   = (const float*)d_in[3];
    const float* w_hh   = (const float*)d_in[4];
    const float* b_ih   = (const float*)d_in[5];
    const float* b_hh   = (const float*)d_in[6];
    const float* last_w = (const float*)d_in[7];
    const float* last_b = (const float*)d_in[8];
    float* out = (float*)d_out;

    f16* gates3 = (f16*)d_ws;   // TPAD*16*640*2 = 41,984,000 B

    conv_gemm<<<256, 512, 0, stream>>>(inp, conv_w, conv_b, w_ih, b_ih, b_hh, gates3);
    lstm_scan<<<16, 512, 0, stream>>>(gates3, w_hh, last_w, last_b, out);
}